// Round 13
// baseline (169.275 us; speedup 1.0000x reference)
//
#include <hip/hip_runtime.h>
#include <hip/hip_bf16.h>

#define B_ 4
#define N_ 4096
#define C_ 256
#define D_ 32
#define LOG2E 1.44269504088896340736f
#define MFMA16 __builtin_amdgcn_mfma_f32_16x16x32_bf16

typedef __attribute__((ext_vector_type(8))) short short8;   // 8 x bf16 (4 VGPRs)
typedef __attribute__((ext_vector_type(4))) short short4v;  // 4 x bf16 (8 B)
typedef __attribute__((ext_vector_type(4))) float float4v;  // MFMA C/D frag

// cheap round-to-nearest-even fp32->bf16 (finite inputs only): 3 VALU ops
__device__ inline short f2bf_rne(float f) {
  unsigned u = __builtin_bit_cast(unsigned, f);
  u += 0x7FFFu + ((u >> 16) & 1u);
  return (short)(u >> 16);
}
__device__ inline float bf2f(short s) {
  unsigned u = ((unsigned)(unsigned short)s) << 16;
  return __builtin_bit_cast(float, u);
}
__device__ inline float fast_exp2(float x) { return __builtin_amdgcn_exp2f(x); }

// ---------------------------------------------------------------------------
// Kernel 1: fragment-linearized bf16 weights WtF. Frag f = nb*8+ks.
// Element (f, lane l, j) = W[k][n], n = nb*16+(l&15), k = ks*32+(l>>4)*8+j.
// log2(e) folded into Wq columns.
// ---------------------------------------------------------------------------
__global__ __launch_bounds__(256) void cast_w_kernel(
    const float* __restrict__ Wq, const float* __restrict__ Wk,
    const float* __restrict__ Wv, short* __restrict__ WtF) {
  int i  = blockIdx.x * 256 + threadIdx.x;  // 0..81919
  int j  = i & 7;
  int l  = (i >> 3) & 63;
  int ks = (i >> 9) & 7;
  int nb = i >> 12;
  int n  = nb * 16 + (l & 15);
  int k  = ks * 32 + ((l >> 4) << 3) + j;
  float v;
  if (n < 32)      v = Wq[k * 32 + n] * LOG2E;
  else if (n < 64) v = Wk[k * 32 + (n - 32)];
  else             v = Wv[k * 256 + (n - 64)];
  WtF[i] = f2bf_rne(v);
}

// ---------------------------------------------------------------------------
// Kernel 2: fused QKV projection v3 (unchanged from round 10).
// ---------------------------------------------------------------------------
__global__ __launch_bounds__(256, 2) void proj_kernel(
    const float* __restrict__ x, const short* __restrict__ WtF,
    const float* __restrict__ bq, const float* __restrict__ bk,
    const float* __restrict__ bv,
    short* __restrict__ qb, short* __restrict__ kF, short* __restrict__ vF) {
  int blk = blockIdx.x;
  int b  = blk >> 7;
  int r0 = (blk & 127) * 32;
  int t  = threadIdx.x;
  int w  = t >> 6;
  int l  = t & 63;
  int lc = l & 15;
  int q4 = l >> 4;

  __shared__ __align__(16) short sA[32][272];  // 17.4 KB
  __shared__ __align__(16) short sV[256][40];  // 20.5 KB  [ch][row]
  __shared__ __align__(16) short sK[32][36];   // 2.3 KB   [row][d]

  {
    const float* xb = x + (size_t)(b * N_ + r0) * C_;
#pragma unroll
    for (int ch = 0; ch < 8; ch++) {
      int f   = ch * 256 + t;
      int row = f >> 6;
      int col = (f & 63) * 4;
      float4v v = *(const float4v*)(xb + f * 4);
      short4v s;
      s[0] = f2bf_rne(v[0]); s[1] = f2bf_rne(v[1]);
      s[2] = f2bf_rne(v[2]); s[3] = f2bf_rne(v[3]);
      *(short4v*)(&sA[row][col]) = s;
    }
  }
  __syncthreads();

  float4v acc[10];  // [nbo*2 + rt]
#pragma unroll
  for (int i = 0; i < 10; i++) { acc[i][0] = 0.f; acc[i][1] = 0.f; acc[i][2] = 0.f; acc[i][3] = 0.f; }

  const short* wbase = WtF + w * 4096 + l * 8;  // frag(nbo,ks) at + nbo*16384 + ks*512

#define LOADW(B0, B1, B2, B3, B4, KS)                       \
  B0 = *(const short8*)(wbase + (KS) * 512 + 0 * 16384);    \
  B1 = *(const short8*)(wbase + (KS) * 512 + 1 * 16384);    \
  B2 = *(const short8*)(wbase + (KS) * 512 + 2 * 16384);    \
  B3 = *(const short8*)(wbase + (KS) * 512 + 3 * 16384);    \
  B4 = *(const short8*)(wbase + (KS) * 512 + 4 * 16384);

#define DO_MFMA(A0, A1, B0, B1, B2, B3, B4)                 \
  acc[0] = MFMA16(A0, B0, acc[0], 0, 0, 0);                 \
  acc[1] = MFMA16(A1, B0, acc[1], 0, 0, 0);                 \
  acc[2] = MFMA16(A0, B1, acc[2], 0, 0, 0);                 \
  acc[3] = MFMA16(A1, B1, acc[3], 0, 0, 0);                 \
  acc[4] = MFMA16(A0, B2, acc[4], 0, 0, 0);                 \
  acc[5] = MFMA16(A1, B2, acc[5], 0, 0, 0);                 \
  acc[6] = MFMA16(A0, B3, acc[6], 0, 0, 0);                 \
  acc[7] = MFMA16(A1, B3, acc[7], 0, 0, 0);                 \
  acc[8] = MFMA16(A0, B4, acc[8], 0, 0, 0);                 \
  acc[9] = MFMA16(A1, B4, acc[9], 0, 0, 0);

  short8 wA0, wA1, wA2, wA3, wA4, wB0, wB1, wB2, wB3, wB4;
  LOADW(wA0, wA1, wA2, wA3, wA4, 0)
#pragma unroll
  for (int kk = 0; kk < 8; kk += 2) {
    short8 a00 = *(const short8*)(&sA[lc][kk * 32 + q4 * 8]);
    short8 a01 = *(const short8*)(&sA[16 + lc][kk * 32 + q4 * 8]);
    LOADW(wB0, wB1, wB2, wB3, wB4, kk + 1)
    DO_MFMA(a00, a01, wA0, wA1, wA2, wA3, wA4)
    short8 a10 = *(const short8*)(&sA[lc][(kk + 1) * 32 + q4 * 8]);
    short8 a11 = *(const short8*)(&sA[16 + lc][(kk + 1) * 32 + q4 * 8]);
    LOADW(wA0, wA1, wA2, wA3, wA4, kk + 2)  // kk+2==8: harmless in-ws overread
    DO_MFMA(a10, a11, wB0, wB1, wB2, wB3, wB4)
  }
#undef LOADW
#undef DO_MFMA

  // epilogue: bias + cast; q scatter (tiny), k -> sK, v -> sV (b64 packed)
  {
    float bias0 = (w < 2) ? bq[w * 16 + lc] * LOG2E : bk[(w - 2) * 16 + lc];
#pragma unroll
    for (int rt = 0; rt < 2; rt++) {
      if (w < 2) {
#pragma unroll
        for (int r = 0; r < 4; r++) {
          int row = rt * 16 + q4 * 4 + r;
          qb[(size_t)(b * N_ + r0 + row) * D_ + w * 16 + lc] =
              f2bf_rne(acc[rt][r] + bias0);
        }
      } else {
#pragma unroll
        for (int r = 0; r < 4; r++) {
          int row = rt * 16 + q4 * 4 + r;
          sK[row][(w - 2) * 16 + lc] = f2bf_rne(acc[rt][r] + bias0);
        }
      }
    }
#pragma unroll
    for (int nbo = 1; nbo < 5; nbo++) {
      float bias = bv[(nbo - 1) * 64 + w * 16 + lc];
#pragma unroll
      for (int rt = 0; rt < 2; rt++) {
        float4v a = acc[nbo * 2 + rt];
        short4v pk;
        pk[0] = f2bf_rne(a[0] + bias); pk[1] = f2bf_rne(a[1] + bias);
        pk[2] = f2bf_rne(a[2] + bias); pk[3] = f2bf_rne(a[3] + bias);
        *(short4v*)(&sV[(nbo - 1) * 64 + w * 16 + lc][rt * 16 + q4 * 4]) = pk;
      }
    }
  }
  __syncthreads();

  int kt  = r0 >> 6;          // kv-tile these 32 rows belong to
  int ks0 = (r0 >> 5) & 1;    // which 32-kv half of the tile

  // vF writer: thread t writes 64 B CONTIGUOUS at tb2 + t*64B.
  {
    size_t tb2 = ((size_t)(b * 64 + kt) * 32 + ks0 * 16) * 512;
    int cb = t >> 4;
#pragma unroll
    for (int k = 0; k < 4; k++) {
      int p = (t & 15) * 4 + k;
      int j = p >> 4, i = p & 15;
      short8 vv = *(const short8*)(&sV[cb * 16 + i][j * 8]);
      *(short8*)(vF + tb2 + (size_t)t * 32 + k * 8) = vv;
    }
  }
  // kF writer: threads 0..127 write 16 B contiguous each.
  if (t < 128) {
    int fr = t >> 6, ll = t & 63;
    int kv = fr * 16 + (ll & 15), dg = ll >> 4;
    size_t tbk = ((size_t)(b * 64 + kt) * 4 + ks0 * 2) * 512;
    short8 kv8 = *(const short8*)(&sK[kv][dg * 8]);
    *(short8*)(kF + tbk + (size_t)t * 8) = kv8;
  }
}

// ---------------------------------------------------------------------------
// Kernel 3a: flash partial v4 — 4 BLOCKS/CU. 1024 blocks x 512 thr,
// __launch_bounds__(512, 8) (VGPR cap 64; current state fits ~56-60).
// Block = (b, qt 32 q-rows, kv-half hb). R7-style mixed waves: waves 0-1
// QK rowtile rq + PV; all 8 waves PV on 32-ch slices. V single-buffered,
// reload-after-use (drain hidden by the 3 other co-resident blocks).
// sP LDS-dbuf, 1 barrier/tile. Slot layout: s = w*4 + rt2*2 + cbo.
// ---------------------------------------------------------------------------
__global__ __launch_bounds__(512, 8) void flash_partial_kernel(
    const short* __restrict__ qb, const short* __restrict__ kF,
    const short* __restrict__ vF, short* __restrict__ obuf,
    float* __restrict__ lbuf) {
  int blk = blockIdx.x;
  int b  = blk & 3;            // XCD (blk%8) <-> (b,hb): K/V-half L2-resident
  int hb = (blk >> 2) & 1;
  int qt = blk >> 3;           // 0..127 (32-row Q tiles)
  int r0 = qt * 32;
  int t  = threadIdx.x;
  int w  = t >> 6;
  int l  = t & 63;
  int lc = l & 15;
  int q4 = l >> 4;
  int rq = w & 1;              // QK rowtile for waves 0-1
  bool qkw = (w < 2);

  __shared__ __align__(16) short sP[2][32][72];  // 9.2 KB, [q][kv]

  int p = (b * 128 + qt) * 2 + hb;

  // Q as B-frag (n=q, k=d); log2e pre-folded
  short8 qf = *(const short8*)(qb + (size_t)(b * N_ + r0 + rq * 16 + lc) * D_ + q4 * 8);

  const short* kbp = kF + ((size_t)(b * 64 + hb * 32) * 4) * 512 + l * 8;
  const short* vbp = vF + ((size_t)(b * 64 + hb * 32) * 32 + 2 * w) * 512 + l * 8;

  short8 kC0, kC1, kC2, kC3;   // K A-frags (QK waves; reload-after-use)
  short8 vC0, vC1, vC2, vC3;   // V B-frags [ks*2+cbo] (single-buffered)

  if (qkw) {
    kC0 = *(const short8*)(kbp + 0);
    kC1 = *(const short8*)(kbp + 512);
    kC2 = *(const short8*)(kbp + 1024);
    kC3 = *(const short8*)(kbp + 1536);
  }
  vC0 = *(const short8*)(vbp + 0);
  vC1 = *(const short8*)(vbp + 512);
  vC2 = *(const short8*)(vbp + 8192);
  vC3 = *(const short8*)(vbp + 8704);

  float4v O[4];  // [rt2*2 + cbo]: 32 q x 32 ch
#pragma unroll
  for (int i = 0; i < 4; i++) { O[i][0] = 0.f; O[i][1] = 0.f; O[i][2] = 0.f; O[i][3] = 0.f; }
  float l_part = 0.f;

#define K_RELOAD(TI)                                                           \
  { size_t o_ = (size_t)(TI) * 2048;                                           \
    kC0 = *(const short8*)(kbp + o_);                                          \
    kC1 = *(const short8*)(kbp + o_ + 512);                                    \
    kC2 = *(const short8*)(kbp + o_ + 1024);                                   \
    kC3 = *(const short8*)(kbp + o_ + 1536); }

#define V_RELOAD(TI)                                                           \
  { size_t vo = (size_t)(TI) * 16384;                                          \
    vC0 = *(const short8*)(vbp + vo);                                          \
    vC1 = *(const short8*)(vbp + vo + 512);                                    \
    vC2 = *(const short8*)(vbp + vo + 8192);                                   \
    vC3 = *(const short8*)(vbp + vo + 8704); }

#define QK_STEP(SPB, VALID)                                                    \
  { float4v z; z[0] = 0.f; z[1] = 0.f; z[2] = 0.f; z[3] = 0.f;                 \
    float4v S0 = MFMA16(kC0, qf, z, 0, 0, 0);                                  \
    float4v S1 = MFMA16(kC1, qf, z, 0, 0, 0);                                  \
    float4v S2 = MFMA16(kC2, qf, z, 0, 0, 0);                                  \
    float4v S3 = MFMA16(kC3, qf, z, 0, 0, 0);                                  \
    short* rowp = &sP[SPB][rq * 16 + lc][q4 * 4];                              \
    float ts = 0.f;                                                            \
    { float p0 = fast_exp2(S0[0]), p1 = fast_exp2(S0[1]);                      \
      float p2 = fast_exp2(S0[2]), p3 = fast_exp2(S0[3]);                      \
      ts += (p0 + p1) + (p2 + p3);                                             \
      short4v pk; pk[0] = f2bf_rne(p0); pk[1] = f2bf_rne(p1);                  \
      pk[2] = f2bf_rne(p2); pk[3] = f2bf_rne(p3);                              \
      *(short4v*)(rowp + 0) = pk; }                                            \
    { float p0 = fast_exp2(S1[0]), p1 = fast_exp2(S1[1]);                      \
      float p2 = fast_exp2(S1[2]), p3 = fast_exp2(S1[3]);                      \
      ts += (p0 + p1) + (p2 + p3);                                             \
      short4v pk; pk[0] = f2bf_rne(p0); pk[1] = f2bf_rne(p1);                  \
      pk[2] = f2bf_rne(p2); pk[3] = f2bf_rne(p3);                              \
      *(short4v*)(rowp + 16) = pk; }                                           \
    { float p0 = fast_exp2(S2[0]), p1 = fast_exp2(S2[1]);                      \
      float p2 = fast_exp2(S2[2]), p3 = fast_exp2(S2[3]);                      \
      ts += (p0 + p1) + (p2 + p3);                                             \
      short4v pk; pk[0] = f2bf_rne(p0); pk[1] = f2bf_rne(p1);                  \
      pk[2] = f2bf_rne(p2); pk[3] = f2bf_rne(p3);                              \
      *(short4v*)(rowp + 32) = pk; }                                           \
    { float p0 = fast_exp2(S3[0]), p1 = fast_exp2(S3[1]);                      \
      float p2 = fast_exp2(S3[2]), p3 = fast_exp2(S3[3]);                      \
      ts += (p0 + p1) + (p2 + p3);                                             \
      short4v pk; pk[0] = f2bf_rne(p0); pk[1] = f2bf_rne(p1);                  \
      pk[2] = f2bf_rne(p2); pk[3] = f2bf_rne(p3);                              \
      *(short4v*)(rowp + 48) = pk; }                                           \
    if (VALID) l_part += ts; }

#define PV_STEP(SPB)                                                           \
  { _Pragma("unroll")                                                          \
    for (int rt2 = 0; rt2 < 2; rt2++) {                                        \
      short8 pf0 = *(const short8*)(&sP[SPB][rt2 * 16 + lc][q4 * 8]);          \
      short8 pf1 = *(const short8*)(&sP[SPB][rt2 * 16 + lc][32 + q4 * 8]);     \
      O[rt2 * 2 + 0] = MFMA16(pf0, vC0, O[rt2 * 2 + 0], 0, 0, 0);              \
      O[rt2 * 2 + 0] = MFMA16(pf1, vC2, O[rt2 * 2 + 0], 0, 0, 0);              \
      O[rt2 * 2 + 1] = MFMA16(pf0, vC1, O[rt2 * 2 + 1], 0, 0, 0);              \
      O[rt2 * 2 + 1] = MFMA16(pf1, vC3, O[rt2 * 2 + 1], 0, 0, 0);              \
    } }

  if (qkw) {
    QK_STEP(0, true)
    K_RELOAD(1)
  }
  __syncthreads();

  for (int ti = 0; ti < 32; ti += 2) {
    int n1 = ti + 1;
    int n2 = (ti + 2 < 32) ? ti + 2 : 31;
    bool v2 = (ti + 2 < 32);
    int n3 = (ti + 3 < 32) ? ti + 3 : 31;

    // ---- half A: QK(n1)->sP1 (waves 0-1) || PV(ti) from sP0 (all) ----
    if (qkw) {
      QK_STEP(1, true)
      K_RELOAD(n2)
    }
    PV_STEP(0)
    V_RELOAD(n1)     // next tile's V; pre-barrier drain covers RAW for half B
    __syncthreads();

    // ---- half B: QK(n2)->sP0 || PV(n1) from sP1 ----
    if (qkw) {
      QK_STEP(0, v2)   // clamped tail recompute; l not double-counted
      K_RELOAD(n3)
    }
    PV_STEP(1)
    V_RELOAD(n2)
    __syncthreads();
  }
#undef K_RELOAD
#undef V_RELOAD
#undef QK_STEP
#undef PV_STEP

  // ---- store O partial, slot s = w*4 + rt2*2 + cbo (512 B each) ----
  {
    short* ob = obuf + ((size_t)p * 32 + w * 4) * 256 + l * 4;
#pragma unroll
    for (int a = 0; a < 4; a++) {
      float4v o = O[a];
      short4v pk;
      pk[0] = f2bf_rne(o[0]); pk[1] = f2bf_rne(o[1]);
      pk[2] = f2bf_rne(o[2]); pk[3] = f2bf_rne(o[3]);
      *(short4v*)(ob + a * 256) = pk;
    }
  }
  if (qkw) {
    float l_tot = l_part + __shfl_xor(l_part, 16, 64);
    l_tot += __shfl_xor(l_tot, 32, 64);
    if (q4 == 0) lbuf[(size_t)p * 32 + rq * 16 + lc] = l_tot;
  }
}

// ---------------------------------------------------------------------------
// Kernel 3b: merge v3 — 512 blocks x 256 thr (4/CU), one 32-row tile each.
// Coalesced via LDS. Slot decode: s = w*4 + rt2*2 + cbo; within slot lane l'
// holds 4 shorts (r): row = rt2*16+(l'>>4)*4+r, ch = w*32+cbo*16+(l'&15).
// ---------------------------------------------------------------------------
__global__ __launch_bounds__(256) void merge_kernel(
    const short* __restrict__ obuf, const float* __restrict__ lbuf,
    const float* __restrict__ xin, const float* __restrict__ gptr,
    float* __restrict__ out) {
  int blk = blockIdx.x;   // = b*128 + qt (32-row tiles)
  int t   = threadIdx.x;
  float g = *gptr;

  __shared__ float sS[32][260];  // 33.3 KB
  __shared__ float sLinv[32];

  const short* o0 = obuf + (size_t)(blk * 2 + 0) * 8192;
  const short* o1 = obuf + (size_t)(blk * 2 + 1) * 8192;
  const float* l0 = lbuf + (size_t)(blk * 2 + 0) * 32;
  const float* l1 = lbuf + (size_t)(blk * 2 + 1) * 32;
  size_t gbase = (size_t)blk * 8192;  // floats (32 rows x 256 ch)

  if (t < 32) sLinv[t] = __builtin_amdgcn_rcpf(l0[t] + l1[t]);

  // ---- phase 1: coalesced partial reads -> fp32 sums in LDS ----
#pragma unroll
  for (int j = 0; j < 4; j++) {
    int gdx  = j * 256 + t;       // 0..1023 16B-units (16 KB partial)
    int w8   = gdx >> 7;          // slot group w (0..7), 2 KB each
    int within = gdx & 127;       // 4 slots x 32 short8
    int s_in = within >> 5;       // rt2*2 + cbo
    int pos8 = within & 31;
    int offs = (w8 * 4 + s_in) * 256 + pos8 * 8;  // shorts
    short8 a8 = *(const short8*)(o0 + offs);
    short8 c8 = *(const short8*)(o1 + offs);
    int rt2 = s_in >> 1;
    int cbo = s_in & 1;
    int chB = w8 * 32 + cbo * 16;
#pragma unroll
    for (int e = 0; e < 8; e++) {
      int lane = pos8 * 2 + (e >> 2);
      int r    = e & 3;
      int row  = rt2 * 16 + (lane >> 4) * 4 + r;
      int ch   = chB + (lane & 15);
      sS[row][ch] = bf2f(a8[e]) + bf2f(c8[e]);
    }
  }
  __syncthreads();

  // ---- phase 2: coalesced out = g*(sum*linv) + x ----
#pragma unroll
  for (int j = 0; j < 8; j++) {
    int gdx = j * 1024 + t * 4;   // float index within 32 KB tile
    int row = gdx >> 8;
    int ch  = gdx & 255;
    float linv = sLinv[row];
    size_t gi = gbase + gdx;
    float4v xv = *(const float4v*)(xin + gi);
    float4v sv = *(const float4v*)(&sS[row][ch]);
    float4v ov;
#pragma unroll
    for (int e = 0; e < 4; e++) ov[e] = g * (sv[e] * linv) + xv[e];
    *(float4v*)(out + gi) = ov;
  }
}

// ---------------------------------------------------------------------------
extern "C" void kernel_launch(void* const* d_in, const int* in_sizes, int n_in,
                              void* d_out, int out_size, void* d_ws, size_t ws_size,
                              hipStream_t stream) {
  const float* x     = (const float*)d_in[0];
  const float* Wq    = (const float*)d_in[1];
  const float* bq    = (const float*)d_in[2];
  const float* Wk    = (const float*)d_in[3];
  const float* bk    = (const float*)d_in[4];
  const float* Wv    = (const float*)d_in[5];
  const float* bv    = (const float*)d_in[6];
  const float* gamma = (const float*)d_in[7];
  float* out = (float*)d_out;

  char* ws = (char*)d_ws;
  short* qb   = (short*)ws;                   // 1 MB   row-major [N][32]
  short* kF   = (short*)(ws + (1u << 20));    // 1 MB   fragment-linear
  short* vF   = (short*)(ws + (2u << 20));    // 8 MB   fragment-linear
  short* WtF  = (short*)(ws + (10u << 20));   // 160 KB fragment-linear
  short* obuf = (short*)(ws + (11u << 20));   // 16 MB  bf16 partial O (slot layout)
  float* lbuf = (float*)(ws + (28u << 20));   // 128 KB fp32 partial l [1024][32]

  hipLaunchKernelGGL(cast_w_kernel,        dim3(320),  dim3(256), 0, stream, Wq, Wk, Wv, WtF);
  hipLaunchKernelGGL(proj_kernel,          dim3(512),  dim3(256), 0, stream, x, WtF, bq, bk, bv, qb, kF, vF);
  hipLaunchKernelGGL(flash_partial_kernel, dim3(1024), dim3(512), 0, stream, qb, kF, vF, obuf, lbuf);
  hipLaunchKernelGGL(merge_kernel,         dim3(512),  dim3(256), 0, stream, obuf, lbuf, x, gamma, out);
}

// Round 14
// 142.166 us; speedup vs baseline: 1.1907x; 1.1907x over previous
//
#include <hip/hip_runtime.h>
#include <hip/hip_bf16.h>

#define B_ 4
#define N_ 4096
#define C_ 256
#define D_ 32
#define LOG2E 1.44269504088896340736f
#define MFMA16 __builtin_amdgcn_mfma_f32_16x16x32_bf16

typedef __attribute__((ext_vector_type(8))) short short8;   // 8 x bf16 (4 VGPRs)
typedef __attribute__((ext_vector_type(4))) short short4v;  // 4 x bf16 (8 B)
typedef __attribute__((ext_vector_type(4))) float float4v;  // MFMA C/D frag

// cheap round-to-nearest-even fp32->bf16 (finite inputs only): 3 VALU ops
__device__ inline short f2bf_rne(float f) {
  unsigned u = __builtin_bit_cast(unsigned, f);
  u += 0x7FFFu + ((u >> 16) & 1u);
  return (short)(u >> 16);
}
__device__ inline float bf2f(short s) {
  unsigned u = ((unsigned)(unsigned short)s) << 16;
  return __builtin_bit_cast(float, u);
}
__device__ inline float fast_exp2(float x) { return __builtin_amdgcn_exp2f(x); }

// ---------------------------------------------------------------------------
// Kernel 1: fragment-linearized bf16 weights WtF. Frag f = nb*8+ks.
// Element (f, lane l, j) = W[k][n], n = nb*16+(l&15), k = ks*32+(l>>4)*8+j.
// log2(e) folded into Wq columns.
// ---------------------------------------------------------------------------
__global__ __launch_bounds__(256) void cast_w_kernel(
    const float* __restrict__ Wq, const float* __restrict__ Wk,
    const float* __restrict__ Wv, short* __restrict__ WtF) {
  int i  = blockIdx.x * 256 + threadIdx.x;  // 0..81919
  int j  = i & 7;
  int l  = (i >> 3) & 63;
  int ks = (i >> 9) & 7;
  int nb = i >> 12;
  int n  = nb * 16 + (l & 15);
  int k  = ks * 32 + ((l >> 4) << 3) + j;
  float v;
  if (n < 32)      v = Wq[k * 32 + n] * LOG2E;
  else if (n < 64) v = Wk[k * 32 + (n - 32)];
  else             v = Wv[k * 256 + (n - 64)];
  WtF[i] = f2bf_rne(v);
}

// ---------------------------------------------------------------------------
// Kernel 2: fused QKV projection v3 (unchanged from round 10).
// ---------------------------------------------------------------------------
__global__ __launch_bounds__(256, 2) void proj_kernel(
    const float* __restrict__ x, const short* __restrict__ WtF,
    const float* __restrict__ bq, const float* __restrict__ bk,
    const float* __restrict__ bv,
    short* __restrict__ qb, short* __restrict__ kF, short* __restrict__ vF) {
  int blk = blockIdx.x;
  int b  = blk >> 7;
  int r0 = (blk & 127) * 32;
  int t  = threadIdx.x;
  int w  = t >> 6;
  int l  = t & 63;
  int lc = l & 15;
  int q4 = l >> 4;

  __shared__ __align__(16) short sA[32][272];  // 17.4 KB
  __shared__ __align__(16) short sV[256][40];  // 20.5 KB  [ch][row]
  __shared__ __align__(16) short sK[32][36];   // 2.3 KB   [row][d]

  {
    const float* xb = x + (size_t)(b * N_ + r0) * C_;
#pragma unroll
    for (int ch = 0; ch < 8; ch++) {
      int f   = ch * 256 + t;
      int row = f >> 6;
      int col = (f & 63) * 4;
      float4v v = *(const float4v*)(xb + f * 4);
      short4v s;
      s[0] = f2bf_rne(v[0]); s[1] = f2bf_rne(v[1]);
      s[2] = f2bf_rne(v[2]); s[3] = f2bf_rne(v[3]);
      *(short4v*)(&sA[row][col]) = s;
    }
  }
  __syncthreads();

  float4v acc[10];  // [nbo*2 + rt]
#pragma unroll
  for (int i = 0; i < 10; i++) { acc[i][0] = 0.f; acc[i][1] = 0.f; acc[i][2] = 0.f; acc[i][3] = 0.f; }

  const short* wbase = WtF + w * 4096 + l * 8;  // frag(nbo,ks) at + nbo*16384 + ks*512

#define LOADW(B0, B1, B2, B3, B4, KS)                       \
  B0 = *(const short8*)(wbase + (KS) * 512 + 0 * 16384);    \
  B1 = *(const short8*)(wbase + (KS) * 512 + 1 * 16384);    \
  B2 = *(const short8*)(wbase + (KS) * 512 + 2 * 16384);    \
  B3 = *(const short8*)(wbase + (KS) * 512 + 3 * 16384);    \
  B4 = *(const short8*)(wbase + (KS) * 512 + 4 * 16384);

#define DO_MFMA(A0, A1, B0, B1, B2, B3, B4)                 \
  acc[0] = MFMA16(A0, B0, acc[0], 0, 0, 0);                 \
  acc[1] = MFMA16(A1, B0, acc[1], 0, 0, 0);                 \
  acc[2] = MFMA16(A0, B1, acc[2], 0, 0, 0);                 \
  acc[3] = MFMA16(A1, B1, acc[3], 0, 0, 0);                 \
  acc[4] = MFMA16(A0, B2, acc[4], 0, 0, 0);                 \
  acc[5] = MFMA16(A1, B2, acc[5], 0, 0, 0);                 \
  acc[6] = MFMA16(A0, B3, acc[6], 0, 0, 0);                 \
  acc[7] = MFMA16(A1, B3, acc[7], 0, 0, 0);                 \
  acc[8] = MFMA16(A0, B4, acc[8], 0, 0, 0);                 \
  acc[9] = MFMA16(A1, B4, acc[9], 0, 0, 0);

  short8 wA0, wA1, wA2, wA3, wA4, wB0, wB1, wB2, wB3, wB4;
  LOADW(wA0, wA1, wA2, wA3, wA4, 0)
#pragma unroll
  for (int kk = 0; kk < 8; kk += 2) {
    short8 a00 = *(const short8*)(&sA[lc][kk * 32 + q4 * 8]);
    short8 a01 = *(const short8*)(&sA[16 + lc][kk * 32 + q4 * 8]);
    LOADW(wB0, wB1, wB2, wB3, wB4, kk + 1)
    DO_MFMA(a00, a01, wA0, wA1, wA2, wA3, wA4)
    short8 a10 = *(const short8*)(&sA[lc][(kk + 1) * 32 + q4 * 8]);
    short8 a11 = *(const short8*)(&sA[16 + lc][(kk + 1) * 32 + q4 * 8]);
    LOADW(wA0, wA1, wA2, wA3, wA4, kk + 2)  // kk+2==8: harmless in-ws overread
    DO_MFMA(a10, a11, wB0, wB1, wB2, wB3, wB4)
  }
#undef LOADW
#undef DO_MFMA

  // epilogue: bias + cast; q scatter (tiny), k -> sK, v -> sV (b64 packed)
  {
    float bias0 = (w < 2) ? bq[w * 16 + lc] * LOG2E : bk[(w - 2) * 16 + lc];
#pragma unroll
    for (int rt = 0; rt < 2; rt++) {
      if (w < 2) {
#pragma unroll
        for (int r = 0; r < 4; r++) {
          int row = rt * 16 + q4 * 4 + r;
          qb[(size_t)(b * N_ + r0 + row) * D_ + w * 16 + lc] =
              f2bf_rne(acc[rt][r] + bias0);
        }
      } else {
#pragma unroll
        for (int r = 0; r < 4; r++) {
          int row = rt * 16 + q4 * 4 + r;
          sK[row][(w - 2) * 16 + lc] = f2bf_rne(acc[rt][r] + bias0);
        }
      }
    }
#pragma unroll
    for (int nbo = 1; nbo < 5; nbo++) {
      float bias = bv[(nbo - 1) * 64 + w * 16 + lc];
#pragma unroll
      for (int rt = 0; rt < 2; rt++) {
        float4v a = acc[nbo * 2 + rt];
        short4v pk;
        pk[0] = f2bf_rne(a[0] + bias); pk[1] = f2bf_rne(a[1] + bias);
        pk[2] = f2bf_rne(a[2] + bias); pk[3] = f2bf_rne(a[3] + bias);
        *(short4v*)(&sV[(nbo - 1) * 64 + w * 16 + lc][rt * 16 + q4 * 4]) = pk;
      }
    }
  }
  __syncthreads();

  int kt  = r0 >> 6;          // kv-tile these 32 rows belong to
  int ks0 = (r0 >> 5) & 1;    // which 32-kv half of the tile

  // vF writer: thread t writes 64 B CONTIGUOUS at tb2 + t*64B.
  {
    size_t tb2 = ((size_t)(b * 64 + kt) * 32 + ks0 * 16) * 512;
    int cb = t >> 4;
#pragma unroll
    for (int k = 0; k < 4; k++) {
      int p = (t & 15) * 4 + k;
      int j = p >> 4, i = p & 15;
      short8 vv = *(const short8*)(&sV[cb * 16 + i][j * 8]);
      *(short8*)(vF + tb2 + (size_t)t * 32 + k * 8) = vv;
    }
  }
  // kF writer: threads 0..127 write 16 B contiguous each.
  if (t < 128) {
    int fr = t >> 6, ll = t & 63;
    int kv = fr * 16 + (ll & 15), dg = ll >> 4;
    size_t tbk = ((size_t)(b * 64 + kt) * 4 + ks0 * 2) * 512;
    short8 kv8 = *(const short8*)(&sK[kv][dg * 8]);
    *(short8*)(kF + tbk + (size_t)t * 8) = kv8;
  }
}

// ---------------------------------------------------------------------------
// Kernel 3a: flash partial (R10 structure; sP now FRAGMENT-LINEAR in LDS).
// 512 blocks x 512 thr, 2 blocks/CU. Block = (b, qt 64 rows, kv-half hb).
// Waves 0-3: QK rowtile rq + softmax + sP + PV; waves 4-7: PV only; every
// wave owns 32 ch. sP layout: per buf, 8 A-frags (fi = rt*2 + ks), each
// 64 lanes x 8 shorts (1 KB). PV reads are lane-linear b128 -> ZERO bank
// conflicts (R10's 5.3M conflict cycles came from the 144B-stride reads).
// QK writes: b64 at base + {0,256,512,768} shorts (2-4 way, 4/tile, cheap).
// ---------------------------------------------------------------------------
__global__ __launch_bounds__(512, 4) void flash_partial_kernel(
    const short* __restrict__ qb, const short* __restrict__ kF,
    const short* __restrict__ vF, short* __restrict__ obuf,
    float* __restrict__ lbuf) {
  int blk = blockIdx.x;
  int b  = blk & 3;            // XCD (blk%8) <-> (b,hb): K/V-half L2-resident
  int hb = (blk >> 2) & 1;
  int qt = blk >> 3;
  int r0 = qt * 64;
  int t  = threadIdx.x;
  int w  = t >> 6;
  int l  = t & 63;
  int lc = l & 15;
  int q4 = l >> 4;
  int rq = w & 3;
  bool qkw = (w < 4);

  __shared__ __align__(16) short sPn[2][4096];  // 16 KB: [buf][fi*512 + lane*8 + j]

  int p = (b * 64 + qt) * 2 + hb;

  // Q as B-frag (n=q, k=d); log2e pre-folded
  short8 qf = *(const short8*)(qb + (size_t)(b * N_ + r0 + rq * 16 + lc) * D_ + q4 * 8);

  const short* kbp = kF + ((size_t)(b * 64 + hb * 32) * 4) * 512 + l * 8;
  const short* vbp = vF + ((size_t)(b * 64 + hb * 32) * 32 + 2 * w) * 512 + l * 8;

  short8 kC0, kC1, kC2, kC3;
  short8 vX00, vX01, vX10, vX11;
  short8 vY00, vY01, vY10, vY11;

  kC0 = *(const short8*)(kbp + 0);
  kC1 = *(const short8*)(kbp + 512);
  kC2 = *(const short8*)(kbp + 1024);
  kC3 = *(const short8*)(kbp + 1536);
  vX00 = *(const short8*)(vbp + 0);
  vX01 = *(const short8*)(vbp + 512);
  vX10 = *(const short8*)(vbp + 8192);
  vX11 = *(const short8*)(vbp + 8704);

  float4v O[8];  // [rt*2 + cbo]: 64 q x 32 ch
#pragma unroll
  for (int i = 0; i < 8; i++) { O[i][0] = 0.f; O[i][1] = 0.f; O[i][2] = 0.f; O[i][3] = 0.f; }
  float l_part = 0.f;

  // QK write base within a buf: frag fi = rq*2 (+ i>>1), lane-in-frag
  // = ((i&1)*2 + (q4>>1))*16 + lc, slot = (q4&1)*4.  St block i lands at
  // qkbase + i*256 shorts.
  int qkbase = (rq * 2) * 512 + (((q4 >> 1) * 16) + lc) * 8 + (q4 & 1) * 4;

#define K_RELOAD(TI)                                                           \
  { size_t o_ = (size_t)(TI) * 2048;                                           \
    kC0 = *(const short8*)(kbp + o_);                                          \
    kC1 = *(const short8*)(kbp + o_ + 512);                                    \
    kC2 = *(const short8*)(kbp + o_ + 1024);                                   \
    kC3 = *(const short8*)(kbp + o_ + 1536); }

#define QK_STEP(SPB, VALID)                                                    \
  { float4v z; z[0] = 0.f; z[1] = 0.f; z[2] = 0.f; z[3] = 0.f;                 \
    float4v S0 = MFMA16(kC0, qf, z, 0, 0, 0);                                  \
    float4v S1 = MFMA16(kC1, qf, z, 0, 0, 0);                                  \
    float4v S2 = MFMA16(kC2, qf, z, 0, 0, 0);                                  \
    float4v S3 = MFMA16(kC3, qf, z, 0, 0, 0);                                  \
    short* rowp = &sPn[SPB][qkbase];                                           \
    float ts = 0.f;                                                            \
    { float p0 = fast_exp2(S0[0]), p1 = fast_exp2(S0[1]);                      \
      float p2 = fast_exp2(S0[2]), p3 = fast_exp2(S0[3]);                      \
      ts += (p0 + p1) + (p2 + p3);                                             \
      short4v pk; pk[0] = f2bf_rne(p0); pk[1] = f2bf_rne(p1);                  \
      pk[2] = f2bf_rne(p2); pk[3] = f2bf_rne(p3);                              \
      *(short4v*)(rowp + 0) = pk; }                                            \
    { float p0 = fast_exp2(S1[0]), p1 = fast_exp2(S1[1]);                      \
      float p2 = fast_exp2(S1[2]), p3 = fast_exp2(S1[3]);                      \
      ts += (p0 + p1) + (p2 + p3);                                             \
      short4v pk; pk[0] = f2bf_rne(p0); pk[1] = f2bf_rne(p1);                  \
      pk[2] = f2bf_rne(p2); pk[3] = f2bf_rne(p3);                              \
      *(short4v*)(rowp + 256) = pk; }                                          \
    { float p0 = fast_exp2(S2[0]), p1 = fast_exp2(S2[1]);                      \
      float p2 = fast_exp2(S2[2]), p3 = fast_exp2(S2[3]);                      \
      ts += (p0 + p1) + (p2 + p3);                                             \
      short4v pk; pk[0] = f2bf_rne(p0); pk[1] = f2bf_rne(p1);                  \
      pk[2] = f2bf_rne(p2); pk[3] = f2bf_rne(p3);                              \
      *(short4v*)(rowp + 512) = pk; }                                          \
    { float p0 = fast_exp2(S3[0]), p1 = fast_exp2(S3[1]);                      \
      float p2 = fast_exp2(S3[2]), p3 = fast_exp2(S3[3]);                      \
      ts += (p0 + p1) + (p2 + p3);                                             \
      short4v pk; pk[0] = f2bf_rne(p0); pk[1] = f2bf_rne(p1);                  \
      pk[2] = f2bf_rne(p2); pk[3] = f2bf_rne(p3);                              \
      *(short4v*)(rowp + 768) = pk; }                                          \
    if (VALID) l_part += ts; }

#define PV_STEP(SPB, V00, V01, V10, V11)                                       \
  { _Pragma("unroll")                                                          \
    for (int rt = 0; rt < 4; rt++) {                                           \
      short8 pf0 = *(const short8*)(&sPn[SPB][(rt * 2 + 0) * 512 + l * 8]);    \
      short8 pf1 = *(const short8*)(&sPn[SPB][(rt * 2 + 1) * 512 + l * 8]);    \
      O[rt * 2 + 0] = MFMA16(pf0, V00, O[rt * 2 + 0], 0, 0, 0);                \
      O[rt * 2 + 0] = MFMA16(pf1, V10, O[rt * 2 + 0], 0, 0, 0);                \
      O[rt * 2 + 1] = MFMA16(pf0, V01, O[rt * 2 + 1], 0, 0, 0);                \
      O[rt * 2 + 1] = MFMA16(pf1, V11, O[rt * 2 + 1], 0, 0, 0);                \
    } }

  if (qkw) {
    QK_STEP(0, true)
    K_RELOAD(1)
  }
  __syncthreads();

  for (int ti = 0; ti < 32; ti += 2) {
    int n1 = ti + 1;
    int n2 = (ti + 2 < 32) ? ti + 2 : 31;
    bool v2 = (ti + 2 < 32);
    int n3 = (ti + 3 < 32) ? ti + 3 : 31;

    { size_t vo = (size_t)n1 * 16384;
      vY00 = *(const short8*)(vbp + vo);
      vY01 = *(const short8*)(vbp + vo + 512);
      vY10 = *(const short8*)(vbp + vo + 8192);
      vY11 = *(const short8*)(vbp + vo + 8704); }
    if (qkw) {
      QK_STEP(1, true)
      K_RELOAD(n2)
    }
    PV_STEP(0, vX00, vX01, vX10, vX11)
    __syncthreads();

    { size_t vo = (size_t)n2 * 16384;
      vX00 = *(const short8*)(vbp + vo);
      vX01 = *(const short8*)(vbp + vo + 512);
      vX10 = *(const short8*)(vbp + vo + 8192);
      vX11 = *(const short8*)(vbp + vo + 8704); }
    if (qkw) {
      QK_STEP(0, v2)
      K_RELOAD(n3)
    }
    PV_STEP(1, vY00, vY01, vY10, vY11)
    __syncthreads();
  }
#undef K_RELOAD
#undef QK_STEP
#undef PV_STEP

  // ---- store O partials fragment-linear: slot s = w*8 + rt*2 + cbo ----
  {
    short* ob = obuf + ((size_t)p * 64 + w * 8) * 256 + l * 4;
#pragma unroll
    for (int a = 0; a < 8; a++) {
      float4v o = O[a];
      short4v pk;
      pk[0] = f2bf_rne(o[0]); pk[1] = f2bf_rne(o[1]);
      pk[2] = f2bf_rne(o[2]); pk[3] = f2bf_rne(o[3]);
      *(short4v*)(ob + a * 256) = pk;
    }
  }
  if (qkw) {
    float l_tot = l_part + __shfl_xor(l_part, 16, 64);
    l_tot += __shfl_xor(l_tot, 32, 64);
    if (q4 == 0) lbuf[(size_t)p * 64 + rq * 16 + lc] = l_tot;
  }
}

// ---------------------------------------------------------------------------
// Kernel 3b: merge v2.1 — 512 blocks x 256 thr (2/CU): the h-loop of R10's
// merge is split across blocks (blk2 = blk*2 + h). Same coalesced LDS scheme.
// Slot decode: s = w*8 + rt*4?? no: s = w*8 + rt*2 + cbo (R10 layout); half h
// covers rt in {2h, 2h+1} <=> s%8 in [4h, 4h+4).
// ---------------------------------------------------------------------------
__global__ __launch_bounds__(256) void merge_kernel(
    const short* __restrict__ obuf, const float* __restrict__ lbuf,
    const float* __restrict__ xin, const float* __restrict__ gptr,
    float* __restrict__ out) {
  int blk2 = blockIdx.x;        // 0..511
  int blk  = blk2 >> 1;         // = b*64 + qt
  int h    = blk2 & 1;          // q-row half (32 rows)
  int t    = threadIdx.x;
  float g  = *gptr;

  __shared__ float sS[32][260];  // 33.3 KB
  __shared__ float sLinv[32];

  const short* o0 = obuf + (size_t)(blk * 2 + 0) * 16384;
  const short* o1 = obuf + (size_t)(blk * 2 + 1) * 16384;
  const float* l0 = lbuf + (size_t)(blk * 2 + 0) * 64;
  const float* l1 = lbuf + (size_t)(blk * 2 + 1) * 64;
  size_t gbase = (size_t)blk * 16384;  // floats

  if (t < 32) sLinv[t] = __builtin_amdgcn_rcpf(l0[32 * h + t] + l1[32 * h + t]);

  // ---- phase 1: coalesced partial reads -> fp32 sums in LDS ----
#pragma unroll
  for (int j = 0; j < 4; j++) {
    int gdx    = j * 256 + t;      // 0..1023 (16B units for this half)
    int chunk  = gdx >> 7;         // 0..7  (= slot's w)
    int within = gdx & 127;        // 128 x 16B = 2KB = 4 slots
    int offs   = (chunk * 8 + 4 * h) * 256 + within * 8;  // shorts
    short8 a8 = *(const short8*)(o0 + offs);
    short8 c8 = *(const short8*)(o1 + offs);
    int s_in  = within >> 5;       // slot within chunk (0..3)
    int pos8  = within & 31;       // short8 index within slot
    int rt    = 2 * h + (s_in >> 1);
    int cbo   = s_in & 1;
    int chB   = chunk * 32 + cbo * 16;
#pragma unroll
    for (int e = 0; e < 8; e++) {
      int lane = pos8 * 2 + (e >> 2);
      int r    = e & 3;
      int row  = (rt & 1) * 16 + (lane >> 4) * 4 + r;  // row within half
      int ch   = chB + (lane & 15);
      sS[row][ch] = bf2f(a8[e]) + bf2f(c8[e]);
    }
  }
  __syncthreads();

  // ---- phase 2: coalesced out = g*(sum*linv) + x ----
#pragma unroll
  for (int j = 0; j < 8; j++) {
    int gdx = j * 1024 + t * 4;              // float index within 32KB half
    int row = gdx >> 8;                      // row within half (0..31)
    int ch  = gdx & 255;
    float linv = sLinv[row];
    size_t gi = gbase + (size_t)(32 * h) * 256 + gdx;
    float4v xv = *(const float4v*)(xin + gi);
    float4v sv = *(const float4v*)(&sS[row][ch]);
    float4v ov;
#pragma unroll
    for (int e = 0; e < 4; e++) ov[e] = g * (sv[e] * linv) + xv[e];
    *(float4v*)(out + gi) = ov;
  }
}

// ---------------------------------------------------------------------------
extern "C" void kernel_launch(void* const* d_in, const int* in_sizes, int n_in,
                              void* d_out, int out_size, void* d_ws, size_t ws_size,
                              hipStream_t stream) {
  const float* x     = (const float*)d_in[0];
  const float* Wq    = (const float*)d_in[1];
  const float* bq    = (const float*)d_in[2];
  const float* Wk    = (const float*)d_in[3];
  const float* bk    = (const float*)d_in[4];
  const float* Wv    = (const float*)d_in[5];
  const float* bv    = (const float*)d_in[6];
  const float* gamma = (const float*)d_in[7];
  float* out = (float*)d_out;

  char* ws = (char*)d_ws;
  short* qb   = (short*)ws;                   // 1 MB   row-major [N][32]
  short* kF   = (short*)(ws + (1u << 20));    // 1 MB   fragment-linear
  short* vF   = (short*)(ws + (2u << 20));    // 8 MB   fragment-linear
  short* WtF  = (short*)(ws + (10u << 20));   // 160 KB fragment-linear
  short* obuf = (short*)(ws + (11u << 20));   // 16 MB  bf16 partial O (slot layout)
  float* lbuf = (float*)(ws + (28u << 20));   // 128 KB fp32 partial l [512][64]

  hipLaunchKernelGGL(cast_w_kernel,        dim3(320), dim3(256), 0, stream, Wq, Wk, Wv, WtF);
  hipLaunchKernelGGL(proj_kernel,          dim3(512), dim3(256), 0, stream, x, WtF, bq, bk, bv, qb, kF, vF);
  hipLaunchKernelGGL(flash_partial_kernel, dim3(512), dim3(512), 0, stream, qb, kF, vF, obuf, lbuf);
  hipLaunchKernelGGL(merge_kernel,         dim3(512), dim3(256), 0, stream, obuf, lbuf, x, gamma, out);
}

// Round 15
// 138.998 us; speedup vs baseline: 1.2178x; 1.0228x over previous
//
#include <hip/hip_runtime.h>
#include <hip/hip_bf16.h>

#define B_ 4
#define N_ 4096
#define C_ 256
#define D_ 32
#define LOG2E 1.44269504088896340736f
#define MFMA16 __builtin_amdgcn_mfma_f32_16x16x32_bf16

typedef __attribute__((ext_vector_type(8))) short short8;   // 8 x bf16 (4 VGPRs)
typedef __attribute__((ext_vector_type(4))) short short4v;  // 4 x bf16 (8 B)
typedef __attribute__((ext_vector_type(4))) float float4v;  // MFMA C/D frag

// cheap round-to-nearest-even fp32->bf16 (finite inputs only): 3 VALU ops
__device__ inline short f2bf_rne(float f) {
  unsigned u = __builtin_bit_cast(unsigned, f);
  u += 0x7FFFu + ((u >> 16) & 1u);
  return (short)(u >> 16);
}
__device__ inline float bf2f(short s) {
  unsigned u = ((unsigned)(unsigned short)s) << 16;
  return __builtin_bit_cast(float, u);
}
__device__ inline float fast_exp2(float x) { return __builtin_amdgcn_exp2f(x); }

// gfx950 v_cvt_pk_bf16_f32: 2 fp32 -> 2 bf16 (RNE) in ONE VALU op.
__device__ inline short4v pk4_bf16(float p0, float p1, float p2, float p3) {
  union { unsigned u[2]; short4v s; } r;
  asm("v_cvt_pk_bf16_f32 %0, %1, %2" : "=v"(r.u[0]) : "v"(p0), "v"(p1));
  asm("v_cvt_pk_bf16_f32 %0, %1, %2" : "=v"(r.u[1]) : "v"(p2), "v"(p3));
  return r.s;
}

// ---------------------------------------------------------------------------
// Kernel 1: fragment-linearized bf16 weights WtF. Frag f = nb*8+ks.
// Element (f, lane l, j) = W[k][n], n = nb*16+(l&15), k = ks*32+(l>>4)*8+j.
// log2(e) folded into Wq columns.
// ---------------------------------------------------------------------------
__global__ __launch_bounds__(256) void cast_w_kernel(
    const float* __restrict__ Wq, const float* __restrict__ Wk,
    const float* __restrict__ Wv, short* __restrict__ WtF) {
  int i  = blockIdx.x * 256 + threadIdx.x;  // 0..81919
  int j  = i & 7;
  int l  = (i >> 3) & 63;
  int ks = (i >> 9) & 7;
  int nb = i >> 12;
  int n  = nb * 16 + (l & 15);
  int k  = ks * 32 + ((l >> 4) << 3) + j;
  float v;
  if (n < 32)      v = Wq[k * 32 + n] * LOG2E;
  else if (n < 64) v = Wk[k * 32 + (n - 32)];
  else             v = Wv[k * 256 + (n - 64)];
  WtF[i] = f2bf_rne(v);
}

// ---------------------------------------------------------------------------
// Kernel 2: fused QKV projection v3 (unchanged from round 10).
// ---------------------------------------------------------------------------
__global__ __launch_bounds__(256, 2) void proj_kernel(
    const float* __restrict__ x, const short* __restrict__ WtF,
    const float* __restrict__ bq, const float* __restrict__ bk,
    const float* __restrict__ bv,
    short* __restrict__ qb, short* __restrict__ kF, short* __restrict__ vF) {
  int blk = blockIdx.x;
  int b  = blk >> 7;
  int r0 = (blk & 127) * 32;
  int t  = threadIdx.x;
  int w  = t >> 6;
  int l  = t & 63;
  int lc = l & 15;
  int q4 = l >> 4;

  __shared__ __align__(16) short sA[32][272];  // 17.4 KB
  __shared__ __align__(16) short sV[256][40];  // 20.5 KB  [ch][row]
  __shared__ __align__(16) short sK[32][36];   // 2.3 KB   [row][d]

  {
    const float* xb = x + (size_t)(b * N_ + r0) * C_;
#pragma unroll
    for (int ch = 0; ch < 8; ch++) {
      int f   = ch * 256 + t;
      int row = f >> 6;
      int col = (f & 63) * 4;
      float4v v = *(const float4v*)(xb + f * 4);
      short4v s = pk4_bf16(v[0], v[1], v[2], v[3]);
      *(short4v*)(&sA[row][col]) = s;
    }
  }
  __syncthreads();

  float4v acc[10];  // [nbo*2 + rt]
#pragma unroll
  for (int i = 0; i < 10; i++) { acc[i][0] = 0.f; acc[i][1] = 0.f; acc[i][2] = 0.f; acc[i][3] = 0.f; }

  const short* wbase = WtF + w * 4096 + l * 8;  // frag(nbo,ks) at + nbo*16384 + ks*512

#define LOADW(B0, B1, B2, B3, B4, KS)                       \
  B0 = *(const short8*)(wbase + (KS) * 512 + 0 * 16384);    \
  B1 = *(const short8*)(wbase + (KS) * 512 + 1 * 16384);    \
  B2 = *(const short8*)(wbase + (KS) * 512 + 2 * 16384);    \
  B3 = *(const short8*)(wbase + (KS) * 512 + 3 * 16384);    \
  B4 = *(const short8*)(wbase + (KS) * 512 + 4 * 16384);

#define DO_MFMA(A0, A1, B0, B1, B2, B3, B4)                 \
  acc[0] = MFMA16(A0, B0, acc[0], 0, 0, 0);                 \
  acc[1] = MFMA16(A1, B0, acc[1], 0, 0, 0);                 \
  acc[2] = MFMA16(A0, B1, acc[2], 0, 0, 0);                 \
  acc[3] = MFMA16(A1, B1, acc[3], 0, 0, 0);                 \
  acc[4] = MFMA16(A0, B2, acc[4], 0, 0, 0);                 \
  acc[5] = MFMA16(A1, B2, acc[5], 0, 0, 0);                 \
  acc[6] = MFMA16(A0, B3, acc[6], 0, 0, 0);                 \
  acc[7] = MFMA16(A1, B3, acc[7], 0, 0, 0);                 \
  acc[8] = MFMA16(A0, B4, acc[8], 0, 0, 0);                 \
  acc[9] = MFMA16(A1, B4, acc[9], 0, 0, 0);

  short8 wA0, wA1, wA2, wA3, wA4, wB0, wB1, wB2, wB3, wB4;
  LOADW(wA0, wA1, wA2, wA3, wA4, 0)
#pragma unroll
  for (int kk = 0; kk < 8; kk += 2) {
    short8 a00 = *(const short8*)(&sA[lc][kk * 32 + q4 * 8]);
    short8 a01 = *(const short8*)(&sA[16 + lc][kk * 32 + q4 * 8]);
    LOADW(wB0, wB1, wB2, wB3, wB4, kk + 1)
    DO_MFMA(a00, a01, wA0, wA1, wA2, wA3, wA4)
    short8 a10 = *(const short8*)(&sA[lc][(kk + 1) * 32 + q4 * 8]);
    short8 a11 = *(const short8*)(&sA[16 + lc][(kk + 1) * 32 + q4 * 8]);
    LOADW(wA0, wA1, wA2, wA3, wA4, kk + 2)  // kk+2==8: harmless in-ws overread
    DO_MFMA(a10, a11, wB0, wB1, wB2, wB3, wB4)
  }
#undef LOADW
#undef DO_MFMA

  // epilogue: bias + cast; q scatter (tiny), k -> sK, v -> sV (b64 packed)
  {
    float bias0 = (w < 2) ? bq[w * 16 + lc] * LOG2E : bk[(w - 2) * 16 + lc];
#pragma unroll
    for (int rt = 0; rt < 2; rt++) {
      if (w < 2) {
#pragma unroll
        for (int r = 0; r < 4; r++) {
          int row = rt * 16 + q4 * 4 + r;
          qb[(size_t)(b * N_ + r0 + row) * D_ + w * 16 + lc] =
              f2bf_rne(acc[rt][r] + bias0);
        }
      } else {
#pragma unroll
        for (int r = 0; r < 4; r++) {
          int row = rt * 16 + q4 * 4 + r;
          sK[row][(w - 2) * 16 + lc] = f2bf_rne(acc[rt][r] + bias0);
        }
      }
    }
#pragma unroll
    for (int nbo = 1; nbo < 5; nbo++) {
      float bias = bv[(nbo - 1) * 64 + w * 16 + lc];
#pragma unroll
      for (int rt = 0; rt < 2; rt++) {
        float4v a = acc[nbo * 2 + rt];
        short4v pk = pk4_bf16(a[0] + bias, a[1] + bias, a[2] + bias, a[3] + bias);
        *(short4v*)(&sV[(nbo - 1) * 64 + w * 16 + lc][rt * 16 + q4 * 4]) = pk;
      }
    }
  }
  __syncthreads();

  int kt  = r0 >> 6;          // kv-tile these 32 rows belong to
  int ks0 = (r0 >> 5) & 1;    // which 32-kv half of the tile

  // vF writer: thread t writes 64 B CONTIGUOUS at tb2 + t*64B.
  {
    size_t tb2 = ((size_t)(b * 64 + kt) * 32 + ks0 * 16) * 512;
    int cb = t >> 4;
#pragma unroll
    for (int k = 0; k < 4; k++) {
      int p = (t & 15) * 4 + k;
      int j = p >> 4, i = p & 15;
      short8 vv = *(const short8*)(&sV[cb * 16 + i][j * 8]);
      *(short8*)(vF + tb2 + (size_t)t * 32 + k * 8) = vv;
    }
  }
  // kF writer: threads 0..127 write 16 B contiguous each.
  if (t < 128) {
    int fr = t >> 6, ll = t & 63;
    int kv = fr * 16 + (ll & 15), dg = ll >> 4;
    size_t tbk = ((size_t)(b * 64 + kt) * 4 + ks0 * 2) * 512;
    short8 kv8 = *(const short8*)(&sK[kv][dg * 8]);
    *(short8*)(kF + tbk + (size_t)t * 8) = kv8;
  }
}

// ---------------------------------------------------------------------------
// Kernel 3a: flash partial (R14 structure; sP fragment-linear, 1.08M conflict
// cycles). New: v_cvt_pk_bf16_f32 pack in the softmax (16 f2bf = 48 VALU ->
// 8 cvt_pk) and s_setprio(1) on QK waves (the barrier-critical pipe).
// ---------------------------------------------------------------------------
__global__ __launch_bounds__(512, 4) void flash_partial_kernel(
    const short* __restrict__ qb, const short* __restrict__ kF,
    const short* __restrict__ vF, short* __restrict__ obuf,
    float* __restrict__ lbuf) {
  int blk = blockIdx.x;
  int b  = blk & 3;            // XCD (blk%8) <-> (b,hb): K/V-half L2-resident
  int hb = (blk >> 2) & 1;
  int qt = blk >> 3;
  int r0 = qt * 64;
  int t  = threadIdx.x;
  int w  = t >> 6;
  int l  = t & 63;
  int lc = l & 15;
  int q4 = l >> 4;
  int rq = w & 3;
  bool qkw = (w < 4);

  __shared__ __align__(16) short sPn[2][4096];  // 16 KB: [buf][fi*512 + lane*8 + j]

  int p = (b * 64 + qt) * 2 + hb;

  // Q as B-frag (n=q, k=d); log2e pre-folded
  short8 qf = *(const short8*)(qb + (size_t)(b * N_ + r0 + rq * 16 + lc) * D_ + q4 * 8);

  const short* kbp = kF + ((size_t)(b * 64 + hb * 32) * 4) * 512 + l * 8;
  const short* vbp = vF + ((size_t)(b * 64 + hb * 32) * 32 + 2 * w) * 512 + l * 8;

  short8 kC0, kC1, kC2, kC3;
  short8 vX00, vX01, vX10, vX11;
  short8 vY00, vY01, vY10, vY11;

  kC0 = *(const short8*)(kbp + 0);
  kC1 = *(const short8*)(kbp + 512);
  kC2 = *(const short8*)(kbp + 1024);
  kC3 = *(const short8*)(kbp + 1536);
  vX00 = *(const short8*)(vbp + 0);
  vX01 = *(const short8*)(vbp + 512);
  vX10 = *(const short8*)(vbp + 8192);
  vX11 = *(const short8*)(vbp + 8704);

  float4v O[8];  // [rt*2 + cbo]: 64 q x 32 ch
#pragma unroll
  for (int i = 0; i < 8; i++) { O[i][0] = 0.f; O[i][1] = 0.f; O[i][2] = 0.f; O[i][3] = 0.f; }
  float l_part = 0.f;

  // prioritize the barrier-critical QK pipe
  if (qkw) __builtin_amdgcn_s_setprio(1);

  // QK write base within a buf: frag fi = rq*2 (+ i>>1), lane-in-frag
  // = ((i&1)*2 + (q4>>1))*16 + lc, slot = (q4&1)*4.  St block i lands at
  // qkbase + i*256 shorts.
  int qkbase = (rq * 2) * 512 + (((q4 >> 1) * 16) + lc) * 8 + (q4 & 1) * 4;

#define K_RELOAD(TI)                                                           \
  { size_t o_ = (size_t)(TI) * 2048;                                           \
    kC0 = *(const short8*)(kbp + o_);                                          \
    kC1 = *(const short8*)(kbp + o_ + 512);                                    \
    kC2 = *(const short8*)(kbp + o_ + 1024);                                   \
    kC3 = *(const short8*)(kbp + o_ + 1536); }

#define QK_STEP(SPB, VALID)                                                    \
  { float4v z; z[0] = 0.f; z[1] = 0.f; z[2] = 0.f; z[3] = 0.f;                 \
    float4v S0 = MFMA16(kC0, qf, z, 0, 0, 0);                                  \
    float4v S1 = MFMA16(kC1, qf, z, 0, 0, 0);                                  \
    float4v S2 = MFMA16(kC2, qf, z, 0, 0, 0);                                  \
    float4v S3 = MFMA16(kC3, qf, z, 0, 0, 0);                                  \
    short* rowp = &sPn[SPB][qkbase];                                           \
    float ts = 0.f;                                                            \
    { float p0 = fast_exp2(S0[0]), p1 = fast_exp2(S0[1]);                      \
      float p2 = fast_exp2(S0[2]), p3 = fast_exp2(S0[3]);                      \
      ts += (p0 + p1) + (p2 + p3);                                             \
      *(short4v*)(rowp + 0) = pk4_bf16(p0, p1, p2, p3); }                      \
    { float p0 = fast_exp2(S1[0]), p1 = fast_exp2(S1[1]);                      \
      float p2 = fast_exp2(S1[2]), p3 = fast_exp2(S1[3]);                      \
      ts += (p0 + p1) + (p2 + p3);                                             \
      *(short4v*)(rowp + 256) = pk4_bf16(p0, p1, p2, p3); }                    \
    { float p0 = fast_exp2(S2[0]), p1 = fast_exp2(S2[1]);                      \
      float p2 = fast_exp2(S2[2]), p3 = fast_exp2(S2[3]);                      \
      ts += (p0 + p1) + (p2 + p3);                                             \
      *(short4v*)(rowp + 512) = pk4_bf16(p0, p1, p2, p3); }                    \
    { float p0 = fast_exp2(S3[0]), p1 = fast_exp2(S3[1]);                      \
      float p2 = fast_exp2(S3[2]), p3 = fast_exp2(S3[3]);                      \
      ts += (p0 + p1) + (p2 + p3);                                             \
      *(short4v*)(rowp + 768) = pk4_bf16(p0, p1, p2, p3); }                    \
    if (VALID) l_part += ts; }

#define PV_STEP(SPB, V00, V01, V10, V11)                                       \
  { _Pragma("unroll")                                                          \
    for (int rt = 0; rt < 4; rt++) {                                           \
      short8 pf0 = *(const short8*)(&sPn[SPB][(rt * 2 + 0) * 512 + l * 8]);    \
      short8 pf1 = *(const short8*)(&sPn[SPB][(rt * 2 + 1) * 512 + l * 8]);    \
      O[rt * 2 + 0] = MFMA16(pf0, V00, O[rt * 2 + 0], 0, 0, 0);                \
      O[rt * 2 + 0] = MFMA16(pf1, V10, O[rt * 2 + 0], 0, 0, 0);                \
      O[rt * 2 + 1] = MFMA16(pf0, V01, O[rt * 2 + 1], 0, 0, 0);                \
      O[rt * 2 + 1] = MFMA16(pf1, V11, O[rt * 2 + 1], 0, 0, 0);                \
    } }

  if (qkw) {
    QK_STEP(0, true)
    K_RELOAD(1)
  }
  __syncthreads();

  for (int ti = 0; ti < 32; ti += 2) {
    int n1 = ti + 1;
    int n2 = (ti + 2 < 32) ? ti + 2 : 31;
    bool v2 = (ti + 2 < 32);
    int n3 = (ti + 3 < 32) ? ti + 3 : 31;

    { size_t vo = (size_t)n1 * 16384;
      vY00 = *(const short8*)(vbp + vo);
      vY01 = *(const short8*)(vbp + vo + 512);
      vY10 = *(const short8*)(vbp + vo + 8192);
      vY11 = *(const short8*)(vbp + vo + 8704); }
    if (qkw) {
      QK_STEP(1, true)
      K_RELOAD(n2)
    }
    PV_STEP(0, vX00, vX01, vX10, vX11)
    __syncthreads();

    { size_t vo = (size_t)n2 * 16384;
      vX00 = *(const short8*)(vbp + vo);
      vX01 = *(const short8*)(vbp + vo + 512);
      vX10 = *(const short8*)(vbp + vo + 8192);
      vX11 = *(const short8*)(vbp + vo + 8704); }
    if (qkw) {
      QK_STEP(0, v2)
      K_RELOAD(n3)
    }
    PV_STEP(1, vY00, vY01, vY10, vY11)
    __syncthreads();
  }
#undef K_RELOAD
#undef QK_STEP
#undef PV_STEP

  // ---- store O partials fragment-linear: slot s = w*8 + rt*2 + cbo ----
  {
    short* ob = obuf + ((size_t)p * 64 + w * 8) * 256 + l * 4;
#pragma unroll
    for (int a = 0; a < 8; a++) {
      float4v o = O[a];
      *(short4v*)(ob + a * 256) = pk4_bf16(o[0], o[1], o[2], o[3]);
    }
  }
  if (qkw) {
    float l_tot = l_part + __shfl_xor(l_part, 16, 64);
    l_tot += __shfl_xor(l_tot, 32, 64);
    if (q4 == 0) lbuf[(size_t)p * 64 + rq * 16 + lc] = l_tot;
  }
}

// ---------------------------------------------------------------------------
// Kernel 3b: merge v2.1 — 512 blocks x 256 thr; gamma folded into linv.
// ---------------------------------------------------------------------------
__global__ __launch_bounds__(256) void merge_kernel(
    const short* __restrict__ obuf, const float* __restrict__ lbuf,
    const float* __restrict__ xin, const float* __restrict__ gptr,
    float* __restrict__ out) {
  int blk2 = blockIdx.x;        // 0..511
  int blk  = blk2 >> 1;         // = b*64 + qt
  int h    = blk2 & 1;          // q-row half (32 rows)
  int t    = threadIdx.x;
  float g  = *gptr;

  __shared__ float sS[32][260];  // 33.3 KB
  __shared__ float sGLinv[32];

  const short* o0 = obuf + (size_t)(blk * 2 + 0) * 16384;
  const short* o1 = obuf + (size_t)(blk * 2 + 1) * 16384;
  const float* l0 = lbuf + (size_t)(blk * 2 + 0) * 64;
  const float* l1 = lbuf + (size_t)(blk * 2 + 1) * 64;
  size_t gbase = (size_t)blk * 16384;  // floats

  if (t < 32)
    sGLinv[t] = g * __builtin_amdgcn_rcpf(l0[32 * h + t] + l1[32 * h + t]);

  // ---- phase 1: coalesced partial reads -> fp32 sums in LDS ----
#pragma unroll
  for (int j = 0; j < 4; j++) {
    int gdx    = j * 256 + t;      // 0..1023 (16B units for this half)
    int chunk  = gdx >> 7;         // 0..7  (= slot's w)
    int within = gdx & 127;        // 128 x 16B = 2KB = 4 slots
    int offs   = (chunk * 8 + 4 * h) * 256 + within * 8;  // shorts
    short8 a8 = *(const short8*)(o0 + offs);
    short8 c8 = *(const short8*)(o1 + offs);
    int s_in  = within >> 5;       // slot within chunk (0..3)
    int pos8  = within & 31;       // short8 index within slot
    int rt    = 2 * h + (s_in >> 1);
    int cbo   = s_in & 1;
    int chB   = chunk * 32 + cbo * 16;
#pragma unroll
    for (int e = 0; e < 8; e++) {
      int lane = pos8 * 2 + (e >> 2);
      int r    = e & 3;
      int row  = (rt & 1) * 16 + (lane >> 4) * 4 + r;  // row within half
      int ch   = chB + (lane & 15);
      sS[row][ch] = bf2f(a8[e]) + bf2f(c8[e]);
    }
  }
  __syncthreads();

  // ---- phase 2: coalesced out = gl*sum + x (one FMA per element) ----
#pragma unroll
  for (int j = 0; j < 8; j++) {
    int gdx = j * 1024 + t * 4;              // float index within 32KB half
    int row = gdx >> 8;                      // row within half (0..31)
    int ch  = gdx & 255;
    float gl = sGLinv[row];
    size_t gi = gbase + (size_t)(32 * h) * 256 + gdx;
    float4v xv = *(const float4v*)(xin + gi);
    float4v sv = *(const float4v*)(&sS[row][ch]);
    float4v ov;
#pragma unroll
    for (int e = 0; e < 4; e++) ov[e] = sv[e] * gl + xv[e];
    *(float4v*)(out + gi) = ov;
  }
}

// ---------------------------------------------------------------------------
extern "C" void kernel_launch(void* const* d_in, const int* in_sizes, int n_in,
                              void* d_out, int out_size, void* d_ws, size_t ws_size,
                              hipStream_t stream) {
  const float* x     = (const float*)d_in[0];
  const float* Wq    = (const float*)d_in[1];
  const float* bq    = (const float*)d_in[2];
  const float* Wk    = (const float*)d_in[3];
  const float* bk    = (const float*)d_in[4];
  const float* Wv    = (const float*)d_in[5];
  const float* bv    = (const float*)d_in[6];
  const float* gamma = (const float*)d_in[7];
  float* out = (float*)d_out;

  char* ws = (char*)d_ws;
  short* qb   = (short*)ws;                   // 1 MB   row-major [N][32]
  short* kF   = (short*)(ws + (1u << 20));    // 1 MB   fragment-linear
  short* vF   = (short*)(ws + (2u << 20));    // 8 MB   fragment-linear
  short* WtF  = (short*)(ws + (10u << 20));   // 160 KB fragment-linear
  short* obuf = (short*)(ws + (11u << 20));   // 16 MB  bf16 partial O (slot layout)
  float* lbuf = (float*)(ws + (28u << 20));   // 128 KB fp32 partial l [512][64]

  hipLaunchKernelGGL(cast_w_kernel,        dim3(320), dim3(256), 0, stream, Wq, Wk, Wv, WtF);
  hipLaunchKernelGGL(proj_kernel,          dim3(512), dim3(256), 0, stream, x, WtF, bq, bk, bv, qb, kF, vF);
  hipLaunchKernelGGL(flash_partial_kernel, dim3(512), dim3(512), 0, stream, qb, kF, vF, obuf, lbuf);
  hipLaunchKernelGGL(merge_kernel,         dim3(512), dim3(256), 0, stream, obuf, lbuf, x, gamma, out);
}